// Round 3
// baseline (721.985 us; speedup 1.0000x reference)
//
#include <hip/hip_runtime.h>
#include <cstdint>
#include <cstddef>

#define T_TOK 2048
#define H_DIM 1024
#define I_DIM 2816
#define E_NUM 8

typedef __attribute__((ext_vector_type(8))) short bf16x8;
typedef __attribute__((ext_vector_type(4))) float f32x4;

__device__ __forceinline__ uint16_t f2bf(float f) {
  union { float f; uint32_t u; } v; v.f = f;
  uint32_t r = v.u + 0x7FFF + ((v.u >> 16) & 1);
  return (uint16_t)(r >> 16);
}

// ---------------------------------------------------------------- convert x
__global__ void convert_x_kernel(const float* __restrict__ x,
                                 uint16_t* __restrict__ x16) {
  size_t i = ((size_t)blockIdx.x * 256 + threadIdx.x) * 8;
  float4 a = *(const float4*)(x + i);
  float4 b = *(const float4*)(x + i + 4);
  uint4 o;
  o.x = (uint32_t)f2bf(a.x) | ((uint32_t)f2bf(a.y) << 16);
  o.y = (uint32_t)f2bf(a.z) | ((uint32_t)f2bf(a.w) << 16);
  o.z = (uint32_t)f2bf(b.x) | ((uint32_t)f2bf(b.y) << 16);
  o.w = (uint32_t)f2bf(b.z) | ((uint32_t)f2bf(b.w) << 16);
  *(uint4*)(x16 + i) = o;
}

// ------------------------------------------------- weight fp32[K][N] -> bf16[N][K]
__global__ void transpose_conv_kernel(const float* __restrict__ W,
                                      uint16_t* __restrict__ WT,
                                      int K, int N) {
  __shared__ uint16_t tile[64][72];
  const int e = blockIdx.z;
  const int k0 = blockIdx.x * 64;
  const int n0 = blockIdx.y * 64;
  const float* src = W + ((size_t)e * K + k0) * N + n0;
  uint16_t* dst = WT + ((size_t)e * N + n0) * K + k0;
  const int t = threadIdx.x;
#pragma unroll
  for (int i = 0; i < 4; ++i) {
    int idx = t + 256 * i;
    int r = idx >> 4;
    int c4 = (idx & 15) << 2;
    float4 f = *(const float4*)(src + (size_t)r * N + c4);
    tile[r][c4 + 0] = f2bf(f.x);
    tile[r][c4 + 1] = f2bf(f.y);
    tile[r][c4 + 2] = f2bf(f.z);
    tile[r][c4 + 3] = f2bf(f.w);
  }
  __syncthreads();
  const int n = t >> 2;
  const int ks = (t & 3) << 4;
  uint16_t vals[16];
#pragma unroll
  for (int j = 0; j < 16; ++j) vals[j] = tile[ks + j][n];
  *(uint4*)(dst + (size_t)n * K + ks) = *(uint4*)&vals[0];
  *(uint4*)(dst + (size_t)n * K + ks + 8) = *(uint4*)&vals[8];
}

// ---------------------------------------------------------------- router
__global__ void router_kernel(const float* __restrict__ x,
                              const float* __restrict__ gw,
                              float* __restrict__ logits_out,
                              int* __restrict__ counts,
                              int* __restrict__ tok_list,
                              int* __restrict__ meta_e,
                              float* __restrict__ meta_w) {
  int t = blockIdx.x * 4 + (threadIdx.x >> 6);
  int lane = threadIdx.x & 63;
  const float* xr = x + (size_t)t * H_DIM;
  float xv[16];
#pragma unroll
  for (int i = 0; i < 16; ++i) xv[i] = xr[lane + i * 64];
  float lg[E_NUM];
#pragma unroll
  for (int e = 0; e < E_NUM; ++e) {
    const float* g = gw + e * H_DIM;
    float s = 0.f;
#pragma unroll
    for (int i = 0; i < 16; ++i) s += xv[i] * g[lane + i * 64];
#pragma unroll
    for (int off = 32; off > 0; off >>= 1) s += __shfl_down(s, off, 64);
    lg[e] = s;
  }
  if (lane == 0) {
#pragma unroll
    for (int e = 0; e < E_NUM; ++e) logits_out[t * E_NUM + e] = lg[e];
    int e0 = 0; float l0 = lg[0];
    for (int e = 1; e < E_NUM; ++e) if (lg[e] > l0) { l0 = lg[e]; e0 = e; }
    int e1 = -1; float l1 = -1e30f;
    for (int e = 0; e < E_NUM; ++e)
      if (e != e0 && lg[e] > l1) { l1 = lg[e]; e1 = e; }
    float p1 = __expf(l1 - l0);
    float w0 = 1.f / (1.f + p1);
    float w1 = 1.f - w0;
    int s0 = atomicAdd(&counts[e0], 1);
    int s1 = atomicAdd(&counts[e1], 1);
    tok_list[e0 * T_TOK + s0] = t;
    tok_list[e1 * T_TOK + s1] = t;
    meta_e[2 * t]     = (e0 << 16) | s0;
    meta_e[2 * t + 1] = (e1 << 16) | s1;
    meta_w[2 * t]     = w0;
    meta_w[2 * t + 1] = w1;
  }
}

// ---------------------------------------------------------------- prefix sum
__global__ void prefix_kernel(const int* __restrict__ counts,
                              int* __restrict__ base) {
  if (threadIdx.x == 0 && blockIdx.x == 0) {
    int a = 0;
    for (int e = 0; e < E_NUM; ++e) { base[e] = a; a += counts[e]; }
  }
}

// ------------------------------------------------- fused gate+up GEMM + silu*mul
// reg-prefetch + LDS double-buffer, ONE barrier per K-iter
__global__ __launch_bounds__(256, 2) void gemm_gu_kernel(
    const uint16_t* __restrict__ x16, const uint16_t* __restrict__ wgT,
    const uint16_t* __restrict__ wuT, uint16_t* __restrict__ hbuf,
    const int* __restrict__ counts, const int* __restrict__ base,
    const int* __restrict__ tok_list) {
  constexpr int K = H_DIM, NI = I_DIM, BM = 128, BN = 128, BK = 32;
  const int e  = blockIdx.x >> 4;
  const int mt = blockIdx.x & 15;
  const int nt = blockIdx.y;
  const int cnt = counts[e];
  if (mt * BM >= cnt) return;
  const int rbase = base[e];

  __shared__ uint16_t sA[2][BM * BK];
  __shared__ uint16_t sBg[2][BN * BK];
  __shared__ uint16_t sBu[2][BN * BK];

  const int tid  = threadIdx.x;
  const int lane = tid & 63;
  const int wid  = tid >> 6;
  const int quad = lane >> 4;
  const int l16  = lane & 15;
  const int wm   = (wid >> 1) * 64;
  const int wn   = (wid & 1) * 64;

  const int seg  = lane & 3;
  const int row0 = wid * 16 + (lane >> 2);
  const uint16_t* aptr[2];
  const uint16_t* bgptr[2];
  const uint16_t* buptr[2];
#pragma unroll
  for (int r = 0; r < 2; ++r) {
    int slot = mt * BM + row0 + r * 64;
    int s2 = slot < cnt ? slot : cnt - 1;
    int tok = tok_list[e * T_TOK + s2];
    aptr[r] = x16 + (size_t)tok * K + seg * 8;
    int n = nt * BN + row0 + r * 64;
    bgptr[r] = wgT + ((size_t)e * NI + n) * K + seg * 8;
    buptr[r] = wuT + ((size_t)e * NI + n) * K + seg * 8;
  }

  f32x4 accg[4][4], accu[4][4];
#pragma unroll
  for (int i = 0; i < 4; ++i)
#pragma unroll
    for (int j = 0; j < 4; ++j) {
      f32x4 z = {0.f, 0.f, 0.f, 0.f};
      accg[i][j] = z; accu[i][j] = z;
    }

  // prologue: tile 0 -> regs -> LDS buf 0
  {
    uint4 ca[2], cg[2], cu[2];
#pragma unroll
    for (int r = 0; r < 2; ++r) {
      ca[r] = *(const uint4*)(aptr[r]);
      cg[r] = *(const uint4*)(bgptr[r]);
      cu[r] = *(const uint4*)(buptr[r]);
    }
#pragma unroll
    for (int r = 0; r < 2; ++r) {
      const int o = r * 2048 + wid * 512 + lane * 8;
      *(uint4*)&sA[0][o]  = ca[r];
      *(uint4*)&sBg[0][o] = cg[r];
      *(uint4*)&sBu[0][o] = cu[r];
    }
  }
  __syncthreads();

  constexpr int nIter = K / BK;  // 32
  for (int i = 0; i < nIter; ++i) {
    const int p = i & 1;
    const int kn = ((i + 1) < nIter ? (i + 1) : i) * BK;
    // prefetch next tile into regs (no LDS dep -> no drain at barrier)
    uint4 na[2], ng[2], nu[2];
#pragma unroll
    for (int r = 0; r < 2; ++r) {
      na[r] = *(const uint4*)(aptr[r] + kn);
      ng[r] = *(const uint4*)(bgptr[r] + kn);
      nu[r] = *(const uint4*)(buptr[r] + kn);
    }
    // consume current LDS buffer
    bf16x8 af[4], bg[4], bu[4];
#pragma unroll
    for (int ii = 0; ii < 4; ++ii)
      af[ii] = *(const bf16x8*)&sA[p][(wm + ii * 16 + l16) * BK + quad * 8];
#pragma unroll
    for (int j = 0; j < 4; ++j) {
      bg[j] = *(const bf16x8*)&sBg[p][(wn + j * 16 + l16) * BK + quad * 8];
      bu[j] = *(const bf16x8*)&sBu[p][(wn + j * 16 + l16) * BK + quad * 8];
    }
#pragma unroll
    for (int ii = 0; ii < 4; ++ii)
#pragma unroll
      for (int j = 0; j < 4; ++j) {
        accg[ii][j] = __builtin_amdgcn_mfma_f32_16x16x32_bf16(af[ii], bg[j],
                                                              accg[ii][j], 0, 0, 0);
        accu[ii][j] = __builtin_amdgcn_mfma_f32_16x16x32_bf16(af[ii], bu[j],
                                                              accu[ii][j], 0, 0, 0);
      }
    // write prefetched tile to the other LDS buffer
#pragma unroll
    for (int r = 0; r < 2; ++r) {
      const int o = r * 2048 + wid * 512 + lane * 8;
      *(uint4*)&sA[p ^ 1][o]  = na[r];
      *(uint4*)&sBg[p ^ 1][o] = ng[r];
      *(uint4*)&sBu[p ^ 1][o] = nu[r];
    }
    __syncthreads();
  }

  // epilogue: h = silu(g) * u
#pragma unroll
  for (int i = 0; i < 4; ++i) {
#pragma unroll
    for (int r = 0; r < 4; ++r) {
      int sl = mt * BM + wm + i * 16 + quad * 4 + r;
      if (sl < cnt) {
        size_t rowoff = (size_t)(rbase + sl) * NI + (size_t)nt * BN;
#pragma unroll
        for (int j = 0; j < 4; ++j) {
          float g = accg[i][j][r];
          float u = accu[i][j][r];
          float h = g / (1.f + __expf(-g)) * u;
          hbuf[rowoff + wn + j * 16 + l16] = f2bf(h);
        }
      }
    }
  }
}

// ------------------------------------------------- down GEMM, split-K=2
__global__ __launch_bounds__(256, 2) void gemm_down_kernel(
    const uint16_t* __restrict__ hbuf, const uint16_t* __restrict__ wdT,
    float* __restrict__ ybuf0, float* __restrict__ ybuf1,
    const int* __restrict__ counts, const int* __restrict__ base) {
  constexpr int KTOT = I_DIM, N = H_DIM, BM = 128, BN = 128, BK = 32;
  constexpr int KSPL = KTOT / 2;  // 1408
  const int e  = blockIdx.x >> 4;
  const int mt = blockIdx.x & 15;
  const int nt = blockIdx.y;
  const int kz = blockIdx.z;
  const int cnt = counts[e];
  if (mt * BM >= cnt) return;
  const int rbase = base[e];
  const int kbeg = kz * KSPL;
  float* __restrict__ yout = kz ? ybuf1 : ybuf0;

  __shared__ uint16_t sA[2][BM * BK];
  __shared__ uint16_t sB[2][BN * BK];

  const int tid  = threadIdx.x;
  const int lane = tid & 63;
  const int wid  = tid >> 6;
  const int quad = lane >> 4;
  const int l16  = lane & 15;
  const int wm   = (wid >> 1) * 64;
  const int wn   = (wid & 1) * 64;

  const int seg  = lane & 3;
  const int row0 = wid * 16 + (lane >> 2);
  const uint16_t* aptr[2];
  const uint16_t* bptr[2];
#pragma unroll
  for (int r = 0; r < 2; ++r) {
    int slot = mt * BM + row0 + r * 64;
    int s2 = slot < cnt ? slot : cnt - 1;
    aptr[r] = hbuf + (size_t)(rbase + s2) * KTOT + kbeg + seg * 8;
    int n = nt * BN + row0 + r * 64;
    bptr[r] = wdT + ((size_t)e * N + n) * KTOT + kbeg + seg * 8;
  }

  f32x4 acc[4][4];
#pragma unroll
  for (int i = 0; i < 4; ++i)
#pragma unroll
    for (int j = 0; j < 4; ++j) {
      f32x4 z = {0.f, 0.f, 0.f, 0.f};
      acc[i][j] = z;
    }

  {
    uint4 ca[2], cb[2];
#pragma unroll
    for (int r = 0; r < 2; ++r) {
      ca[r] = *(const uint4*)(aptr[r]);
      cb[r] = *(const uint4*)(bptr[r]);
    }
#pragma unroll
    for (int r = 0; r < 2; ++r) {
      const int o = r * 2048 + wid * 512 + lane * 8;
      *(uint4*)&sA[0][o] = ca[r];
      *(uint4*)&sB[0][o] = cb[r];
    }
  }
  __syncthreads();

  constexpr int nIter = KSPL / BK;  // 44
  for (int i = 0; i < nIter; ++i) {
    const int p = i & 1;
    const int kn = ((i + 1) < nIter ? (i + 1) : i) * BK;
    uint4 na[2], nb[2];
#pragma unroll
    for (int r = 0; r < 2; ++r) {
      na[r] = *(const uint4*)(aptr[r] + kn);
      nb[r] = *(const uint4*)(bptr[r] + kn);
    }
    bf16x8 af[4], bf[4];
#pragma unroll
    for (int ii = 0; ii < 4; ++ii)
      af[ii] = *(const bf16x8*)&sA[p][(wm + ii * 16 + l16) * BK + quad * 8];
#pragma unroll
    for (int j = 0; j < 4; ++j)
      bf[j] = *(const bf16x8*)&sB[p][(wn + j * 16 + l16) * BK + quad * 8];
#pragma unroll
    for (int ii = 0; ii < 4; ++ii)
#pragma unroll
      for (int j = 0; j < 4; ++j)
        acc[ii][j] = __builtin_amdgcn_mfma_f32_16x16x32_bf16(af[ii], bf[j],
                                                             acc[ii][j], 0, 0, 0);
#pragma unroll
    for (int r = 0; r < 2; ++r) {
      const int o = r * 2048 + wid * 512 + lane * 8;
      *(uint4*)&sA[p ^ 1][o] = na[r];
      *(uint4*)&sB[p ^ 1][o] = nb[r];
    }
    __syncthreads();
  }

#pragma unroll
  for (int i = 0; i < 4; ++i) {
#pragma unroll
    for (int r = 0; r < 4; ++r) {
      int sl = mt * BM + wm + i * 16 + quad * 4 + r;
      if (sl < cnt) {
        size_t rowoff = (size_t)(rbase + sl) * N + (size_t)nt * BN;
#pragma unroll
        for (int j = 0; j < 4; ++j)
          yout[rowoff + wn + j * 16 + l16] = acc[i][j][r];
      }
    }
  }
}

// ---------------------------------------------------------------- combine
__global__ void combine_kernel(const float* __restrict__ y0,
                               const float* __restrict__ y1,
                               const int* __restrict__ base,
                               const int* __restrict__ meta_e,
                               const float* __restrict__ meta_w,
                               float* __restrict__ out) {
  int t = blockIdx.x;
  int me0 = meta_e[2 * t], me1 = meta_e[2 * t + 1];
  float w0 = meta_w[2 * t], w1 = meta_w[2 * t + 1];
  size_t r0 = (size_t)(base[me0 >> 16] + (me0 & 0xFFFF));
  size_t r1 = (size_t)(base[me1 >> 16] + (me1 & 0xFFFF));
  int c = threadIdx.x * 4;
  float4 a0 = *(const float4*)&y0[r0 * H_DIM + c];
  float4 a1 = *(const float4*)&y1[r0 * H_DIM + c];
  float4 b0 = *(const float4*)&y0[r1 * H_DIM + c];
  float4 b1 = *(const float4*)&y1[r1 * H_DIM + c];
  float4 o;
  o.x = w0 * (a0.x + a1.x) + w1 * (b0.x + b1.x);
  o.y = w0 * (a0.y + a1.y) + w1 * (b0.y + b1.y);
  o.z = w0 * (a0.z + a1.z) + w1 * (b0.z + b1.z);
  o.w = w0 * (a0.w + a1.w) + w1 * (b0.w + b1.w);
  *(float4*)&out[(size_t)t * H_DIM + c] = o;
}

// ---------------------------------------------------------------- launch
extern "C" void kernel_launch(void* const* d_in, const int* in_sizes, int n_in,
                              void* d_out, int out_size, void* d_ws,
                              size_t ws_size, hipStream_t stream) {
  const float* x      = (const float*)d_in[0];
  const float* gate_w = (const float*)d_in[1];
  const float* w_gate = (const float*)d_in[2];
  const float* w_up   = (const float*)d_in[3];
  const float* w_down = (const float*)d_in[4];
  float* out = (float*)d_out;
  float* logits_out = out + (size_t)T_TOK * H_DIM;

  char* ws = (char*)d_ws;
  int*      counts   = (int*)(ws + 0);
  int*      base     = (int*)(ws + 256);
  int*      meta_e   = (int*)(ws + 512);
  float*    meta_w   = (float*)(ws + 16896);
  int*      tok_list = (int*)(ws + 33280);
  uint16_t* x16      = (uint16_t*)(ws + 98816);            // 4 MB
  uint16_t* wgT      = (uint16_t*)(ws + 4293120);          // 46.1 MB
  uint16_t* wuT      = (uint16_t*)(ws + 50430464);         // 46.1 MB
  uint16_t* wdT      = (uint16_t*)(ws + 96567808);         // 46.1 MB
  uint16_t* hbuf     = (uint16_t*)(ws + 142705152);        // 23.1 MB
  float*    ybuf0    = (float*)(ws + 165773824);           // 16.8 MB
  // ybuf1 reuses the wgT region (wgT is dead once gemm_gu completes;
  // stream order makes this safe under graph replay)
  float*    ybuf1    = (float*)(ws + 4293120);
  // total ws use: 182,551,040 bytes (unchanged from R2)

  hipMemsetAsync(counts, 0, E_NUM * sizeof(int), stream);
  convert_x_kernel<<<1024, 256, 0, stream>>>(x, x16);
  router_kernel<<<512, 256, 0, stream>>>(x, gate_w, logits_out, counts,
                                         tok_list, meta_e, meta_w);
  prefix_kernel<<<1, 64, 0, stream>>>(counts, base);
  transpose_conv_kernel<<<dim3(H_DIM / 64, I_DIM / 64, E_NUM), 256, 0, stream>>>(
      w_gate, wgT, H_DIM, I_DIM);
  transpose_conv_kernel<<<dim3(H_DIM / 64, I_DIM / 64, E_NUM), 256, 0, stream>>>(
      w_up, wuT, H_DIM, I_DIM);
  transpose_conv_kernel<<<dim3(I_DIM / 64, H_DIM / 64, E_NUM), 256, 0, stream>>>(
      w_down, wdT, I_DIM, H_DIM);
  gemm_gu_kernel<<<dim3(E_NUM * 16, I_DIM / 128), 256, 0, stream>>>(
      x16, wgT, wuT, hbuf, counts, base, tok_list);
  gemm_down_kernel<<<dim3(E_NUM * 16, H_DIM / 128, 2), 256, 0, stream>>>(
      hbuf, wdT, ybuf0, ybuf1, counts, base);
  combine_kernel<<<T_TOK, 256, 0, stream>>>(ybuf0, ybuf1, base, meta_e, meta_w,
                                            out);
}

// Round 4
// 540.670 us; speedup vs baseline: 1.3354x; 1.3354x over previous
//
#include <hip/hip_runtime.h>
#include <cstdint>
#include <cstddef>

#define T_TOK 2048
#define H_DIM 1024
#define I_DIM 2816
#define E_NUM 8

// padded row strides (elements) — break power-of-2 HBM channel aliasing
#define KP_H 1088   // rows of length H_DIM  (xg, wgT, wuT)   -> 2176 B
#define KP_I 2880   // rows of length I_DIM  (hbuf, wdT)      -> 5760 B
#define YP   1040   // ybuf rows (fp32)                       -> 4160 B

typedef __attribute__((ext_vector_type(8))) short bf16x8;
typedef __attribute__((ext_vector_type(4))) float f32x4;

__device__ __forceinline__ uint16_t f2bf(float f) {
  union { float f; uint32_t u; } v; v.f = f;
  uint32_t r = v.u + 0x7FFF + ((v.u >> 16) & 1);
  return (uint16_t)(r >> 16);
}

// ------------------------------------------------- weight fp32[K][N] -> bf16[N][KP]
__global__ void transpose_conv_kernel(const float* __restrict__ W,
                                      uint16_t* __restrict__ WT,
                                      int K, int N, int KP) {
  __shared__ uint16_t tile[64][72];
  const int e = blockIdx.z;
  const int k0 = blockIdx.x * 64;
  const int n0 = blockIdx.y * 64;
  const float* src = W + ((size_t)e * K + k0) * N + n0;
  uint16_t* dst = WT + ((size_t)e * N + n0) * KP + k0;
  const int t = threadIdx.x;
#pragma unroll
  for (int i = 0; i < 4; ++i) {
    int idx = t + 256 * i;
    int r = idx >> 4;
    int c4 = (idx & 15) << 2;
    float4 f = *(const float4*)(src + (size_t)r * N + c4);
    tile[r][c4 + 0] = f2bf(f.x);
    tile[r][c4 + 1] = f2bf(f.y);
    tile[r][c4 + 2] = f2bf(f.z);
    tile[r][c4 + 3] = f2bf(f.w);
  }
  __syncthreads();
  const int n = t >> 2;
  const int ks = (t & 3) << 4;
  uint16_t vals[16];
#pragma unroll
  for (int j = 0; j < 16; ++j) vals[j] = tile[ks + j][n];
  *(uint4*)(dst + (size_t)n * KP + ks) = *(uint4*)&vals[0];
  *(uint4*)(dst + (size_t)n * KP + ks + 8) = *(uint4*)&vals[8];
}

// ---------------------------------------------------------------- router
__global__ void router_kernel(const float* __restrict__ x,
                              const float* __restrict__ gw,
                              float* __restrict__ logits_out,
                              int* __restrict__ counts,
                              int* __restrict__ meta_e,
                              float* __restrict__ meta_w) {
  int t = blockIdx.x * 4 + (threadIdx.x >> 6);
  int lane = threadIdx.x & 63;
  const float* xr = x + (size_t)t * H_DIM;
  float xv[16];
#pragma unroll
  for (int i = 0; i < 16; ++i) xv[i] = xr[lane + i * 64];
  float lg[E_NUM];
#pragma unroll
  for (int e = 0; e < E_NUM; ++e) {
    const float* g = gw + e * H_DIM;
    float s = 0.f;
#pragma unroll
    for (int i = 0; i < 16; ++i) s += xv[i] * g[lane + i * 64];
#pragma unroll
    for (int off = 32; off > 0; off >>= 1) s += __shfl_down(s, off, 64);
    lg[e] = s;
  }
  if (lane == 0) {
#pragma unroll
    for (int e = 0; e < E_NUM; ++e) logits_out[t * E_NUM + e] = lg[e];
    int e0 = 0; float l0 = lg[0];
    for (int e = 1; e < E_NUM; ++e) if (lg[e] > l0) { l0 = lg[e]; e0 = e; }
    int e1 = -1; float l1 = -1e30f;
    for (int e = 0; e < E_NUM; ++e)
      if (e != e0 && lg[e] > l1) { l1 = lg[e]; e1 = e; }
    float p1 = __expf(l1 - l0);
    float w0 = 1.f / (1.f + p1);
    float w1 = 1.f - w0;
    int s0 = atomicAdd(&counts[e0], 1);
    int s1 = atomicAdd(&counts[e1], 1);
    meta_e[2 * t]     = (e0 << 16) | s0;
    meta_e[2 * t + 1] = (e1 << 16) | s1;
    meta_w[2 * t]     = w0;
    meta_w[2 * t + 1] = w1;
  }
}

// -------------------------------------------- prefix + m-tile schedule
// sched[0] = mcount; sched[1+i] = (e<<8)|mt
__global__ void sched_kernel(const int* __restrict__ counts,
                             int* __restrict__ base,
                             int* __restrict__ sched) {
  if (threadIdx.x == 0 && blockIdx.x == 0) {
    int a = 0, mc = 0;
    for (int e = 0; e < E_NUM; ++e) {
      base[e] = a;
      int nm = (counts[e] + 127) >> 7;
      for (int mt = 0; mt < nm; ++mt) sched[1 + mc++] = (e << 8) | mt;
      a += counts[e];
    }
    sched[0] = mc;
  }
}

// ---------------------------------- gather + convert: xg[slot] rows (bf16, KP_H)
__global__ void gather_conv_kernel(const float* __restrict__ x,
                                   const int* __restrict__ base,
                                   const int* __restrict__ meta_e,
                                   uint16_t* __restrict__ xg) {
  const int t = blockIdx.x;
  const int c = threadIdx.x * 4;
  float4 f = *(const float4*)(x + (size_t)t * H_DIM + c);
  uint2 o;
  o.x = (uint32_t)f2bf(f.x) | ((uint32_t)f2bf(f.y) << 16);
  o.y = (uint32_t)f2bf(f.z) | ((uint32_t)f2bf(f.w) << 16);
  int me0 = meta_e[2 * t], me1 = meta_e[2 * t + 1];
  size_t r0 = (size_t)(base[me0 >> 16] + (me0 & 0xFFFF));
  size_t r1 = (size_t)(base[me1 >> 16] + (me1 & 0xFFFF));
  *(uint2*)(xg + r0 * KP_H + c) = o;
  *(uint2*)(xg + r1 * KP_H + c) = o;
}

// ------------------------------------------------- fused gate+up GEMM + silu*mul
// persistent blocks over (mi fastest, nt) tiles; reg-prefetch + LDS dbuf
__global__ __launch_bounds__(256, 2) void gemm_gu_kernel(
    const uint16_t* __restrict__ xg, const uint16_t* __restrict__ wgT,
    const uint16_t* __restrict__ wuT, uint16_t* __restrict__ hbuf,
    const int* __restrict__ counts, const int* __restrict__ base,
    const int* __restrict__ sched) {
  constexpr int K = H_DIM, BM = 128, BN = 128, BK = 32;
  constexpr int NT = I_DIM / BN;  // 22

  __shared__ uint16_t sA[2][BM * BK];
  __shared__ uint16_t sBg[2][BN * BK];
  __shared__ uint16_t sBu[2][BN * BK];

  const int tid  = threadIdx.x;
  const int lane = tid & 63;
  const int wid  = tid >> 6;
  const int quad = lane >> 4;
  const int l16  = lane & 15;
  const int wm   = (wid >> 1) * 64;
  const int wn   = (wid & 1) * 64;
  const int seg  = lane & 3;
  const int row0 = wid * 16 + (lane >> 2);

  const int mcount = sched[0];
  const int ntiles = mcount * NT;

  for (int tix = blockIdx.x; tix < ntiles; tix += gridDim.x) {
    const int mi = tix % mcount;
    const int nt = tix / mcount;
    const int emt = sched[1 + mi];
    const int e  = emt >> 8;
    const int mt = emt & 255;
    const int cnt = counts[e];
    const int rbase = base[e];

    const uint16_t* aptr[2];
    const uint16_t* bgptr[2];
    const uint16_t* buptr[2];
#pragma unroll
    for (int r = 0; r < 2; ++r) {
      int slot = mt * BM + row0 + r * 64;
      int s2 = slot < cnt ? slot : cnt - 1;
      aptr[r] = xg + (size_t)(rbase + s2) * KP_H + seg * 8;
      int n = nt * BN + row0 + r * 64;
      bgptr[r] = wgT + ((size_t)e * I_DIM + n) * KP_H + seg * 8;
      buptr[r] = wuT + ((size_t)e * I_DIM + n) * KP_H + seg * 8;
    }

    f32x4 accg[4][4], accu[4][4];
#pragma unroll
    for (int i = 0; i < 4; ++i)
#pragma unroll
      for (int j = 0; j < 4; ++j) {
        f32x4 z = {0.f, 0.f, 0.f, 0.f};
        accg[i][j] = z; accu[i][j] = z;
      }

    {
      uint4 ca[2], cg[2], cu[2];
#pragma unroll
      for (int r = 0; r < 2; ++r) {
        ca[r] = *(const uint4*)(aptr[r]);
        cg[r] = *(const uint4*)(bgptr[r]);
        cu[r] = *(const uint4*)(buptr[r]);
      }
#pragma unroll
      for (int r = 0; r < 2; ++r) {
        const int o = r * 2048 + wid * 512 + lane * 8;
        *(uint4*)&sA[0][o]  = ca[r];
        *(uint4*)&sBg[0][o] = cg[r];
        *(uint4*)&sBu[0][o] = cu[r];
      }
    }
    __syncthreads();

    constexpr int nIter = K / BK;  // 32
    for (int i = 0; i < nIter; ++i) {
      const int p = i & 1;
      const int kn = ((i + 1) < nIter ? (i + 1) : i) * BK;
      uint4 na[2], ng[2], nu[2];
#pragma unroll
      for (int r = 0; r < 2; ++r) {
        na[r] = *(const uint4*)(aptr[r] + kn);
        ng[r] = *(const uint4*)(bgptr[r] + kn);
        nu[r] = *(const uint4*)(buptr[r] + kn);
      }
      bf16x8 af[4], bg[4], bu[4];
#pragma unroll
      for (int ii = 0; ii < 4; ++ii)
        af[ii] = *(const bf16x8*)&sA[p][(wm + ii * 16 + l16) * BK + quad * 8];
#pragma unroll
      for (int j = 0; j < 4; ++j) {
        bg[j] = *(const bf16x8*)&sBg[p][(wn + j * 16 + l16) * BK + quad * 8];
        bu[j] = *(const bf16x8*)&sBu[p][(wn + j * 16 + l16) * BK + quad * 8];
      }
#pragma unroll
      for (int ii = 0; ii < 4; ++ii)
#pragma unroll
        for (int j = 0; j < 4; ++j) {
          accg[ii][j] = __builtin_amdgcn_mfma_f32_16x16x32_bf16(af[ii], bg[j],
                                                                accg[ii][j], 0, 0, 0);
          accu[ii][j] = __builtin_amdgcn_mfma_f32_16x16x32_bf16(af[ii], bu[j],
                                                                accu[ii][j], 0, 0, 0);
        }
#pragma unroll
      for (int r = 0; r < 2; ++r) {
        const int o = r * 2048 + wid * 512 + lane * 8;
        *(uint4*)&sA[p ^ 1][o]  = na[r];
        *(uint4*)&sBg[p ^ 1][o] = ng[r];
        *(uint4*)&sBu[p ^ 1][o] = nu[r];
      }
      __syncthreads();
    }

#pragma unroll
    for (int i = 0; i < 4; ++i) {
#pragma unroll
      for (int r = 0; r < 4; ++r) {
        int sl = mt * BM + wm + i * 16 + quad * 4 + r;
        if (sl < cnt) {
          size_t rowoff = (size_t)(rbase + sl) * KP_I + (size_t)nt * BN;
#pragma unroll
          for (int j = 0; j < 4; ++j) {
            float g = accg[i][j][r];
            float u = accu[i][j][r];
            float h = g / (1.f + __expf(-g)) * u;
            hbuf[rowoff + wn + j * 16 + l16] = f2bf(h);
          }
        }
      }
    }
    __syncthreads();  // protect LDS before next tile's prologue
  }
}

// ------------------------------------------------- down GEMM, persistent, split-K=2
__global__ __launch_bounds__(256, 2) void gemm_down_kernel(
    const uint16_t* __restrict__ hbuf, const uint16_t* __restrict__ wdT,
    float* __restrict__ ybuf0, float* __restrict__ ybuf1,
    const int* __restrict__ counts, const int* __restrict__ base,
    const int* __restrict__ sched) {
  constexpr int N = H_DIM, BM = 128, BN = 128, BK = 32;
  constexpr int KSPL = I_DIM / 2;  // 1408
  constexpr int NT = N / BN;       // 8

  __shared__ uint16_t sA[2][BM * BK];
  __shared__ uint16_t sB[2][BN * BK];

  const int tid  = threadIdx.x;
  const int lane = tid & 63;
  const int wid  = tid >> 6;
  const int quad = lane >> 4;
  const int l16  = lane & 15;
  const int wm   = (wid >> 1) * 64;
  const int wn   = (wid & 1) * 64;
  const int seg  = lane & 3;
  const int row0 = wid * 16 + (lane >> 2);

  const int mcount = sched[0];
  const int ntiles = mcount * NT * 2;

  for (int tix = blockIdx.x; tix < ntiles; tix += gridDim.x) {
    const int mi = tix % mcount;
    const int rest = tix / mcount;
    const int nt = rest & 7;
    const int kz = rest >> 3;
    const int emt = sched[1 + mi];
    const int e  = emt >> 8;
    const int mt = emt & 255;
    const int cnt = counts[e];
    const int rbase = base[e];
    const int kbeg = kz * KSPL;
    float* __restrict__ yout = kz ? ybuf1 : ybuf0;

    const uint16_t* aptr[2];
    const uint16_t* bptr[2];
#pragma unroll
    for (int r = 0; r < 2; ++r) {
      int slot = mt * BM + row0 + r * 64;
      int s2 = slot < cnt ? slot : cnt - 1;
      aptr[r] = hbuf + (size_t)(rbase + s2) * KP_I + kbeg + seg * 8;
      int n = nt * BN + row0 + r * 64;
      bptr[r] = wdT + ((size_t)e * N + n) * KP_I + kbeg + seg * 8;
    }

    f32x4 acc[4][4];
#pragma unroll
    for (int i = 0; i < 4; ++i)
#pragma unroll
      for (int j = 0; j < 4; ++j) {
        f32x4 z = {0.f, 0.f, 0.f, 0.f};
        acc[i][j] = z;
      }

    {
      uint4 ca[2], cb[2];
#pragma unroll
      for (int r = 0; r < 2; ++r) {
        ca[r] = *(const uint4*)(aptr[r]);
        cb[r] = *(const uint4*)(bptr[r]);
      }
#pragma unroll
      for (int r = 0; r < 2; ++r) {
        const int o = r * 2048 + wid * 512 + lane * 8;
        *(uint4*)&sA[0][o] = ca[r];
        *(uint4*)&sB[0][o] = cb[r];
      }
    }
    __syncthreads();

    constexpr int nIter = KSPL / BK;  // 44
    for (int i = 0; i < nIter; ++i) {
      const int p = i & 1;
      const int kn = ((i + 1) < nIter ? (i + 1) : i) * BK;
      uint4 na[2], nb[2];
#pragma unroll
      for (int r = 0; r < 2; ++r) {
        na[r] = *(const uint4*)(aptr[r] + kn);
        nb[r] = *(const uint4*)(bptr[r] + kn);
      }
      bf16x8 af[4], bf[4];
#pragma unroll
      for (int ii = 0; ii < 4; ++ii)
        af[ii] = *(const bf16x8*)&sA[p][(wm + ii * 16 + l16) * BK + quad * 8];
#pragma unroll
      for (int j = 0; j < 4; ++j)
        bf[j] = *(const bf16x8*)&sB[p][(wn + j * 16 + l16) * BK + quad * 8];
#pragma unroll
      for (int ii = 0; ii < 4; ++ii)
#pragma unroll
        for (int j = 0; j < 4; ++j)
          acc[ii][j] = __builtin_amdgcn_mfma_f32_16x16x32_bf16(af[ii], bf[j],
                                                               acc[ii][j], 0, 0, 0);
#pragma unroll
      for (int r = 0; r < 2; ++r) {
        const int o = r * 2048 + wid * 512 + lane * 8;
        *(uint4*)&sA[p ^ 1][o] = na[r];
        *(uint4*)&sB[p ^ 1][o] = nb[r];
      }
      __syncthreads();
    }

#pragma unroll
    for (int i = 0; i < 4; ++i) {
#pragma unroll
      for (int r = 0; r < 4; ++r) {
        int sl = mt * BM + wm + i * 16 + quad * 4 + r;
        if (sl < cnt) {
          size_t rowoff = (size_t)(rbase + sl) * YP + (size_t)nt * BN;
#pragma unroll
          for (int j = 0; j < 4; ++j)
            yout[rowoff + wn + j * 16 + l16] = acc[i][j][r];
        }
      }
    }
    __syncthreads();
  }
}

// ---------------------------------------------------------------- combine
__global__ void combine_kernel(const float* __restrict__ y0,
                               const float* __restrict__ y1,
                               const int* __restrict__ base,
                               const int* __restrict__ meta_e,
                               const float* __restrict__ meta_w,
                               float* __restrict__ out) {
  int t = blockIdx.x;
  int me0 = meta_e[2 * t], me1 = meta_e[2 * t + 1];
  float w0 = meta_w[2 * t], w1 = meta_w[2 * t + 1];
  size_t r0 = (size_t)(base[me0 >> 16] + (me0 & 0xFFFF));
  size_t r1 = (size_t)(base[me1 >> 16] + (me1 & 0xFFFF));
  int c = threadIdx.x * 4;
  float4 a0 = *(const float4*)&y0[r0 * YP + c];
  float4 a1 = *(const float4*)&y1[r0 * YP + c];
  float4 b0 = *(const float4*)&y0[r1 * YP + c];
  float4 b1 = *(const float4*)&y1[r1 * YP + c];
  float4 o;
  o.x = w0 * (a0.x + a1.x) + w1 * (b0.x + b1.x);
  o.y = w0 * (a0.y + a1.y) + w1 * (b0.y + b1.y);
  o.z = w0 * (a0.z + a1.z) + w1 * (b0.z + b1.z);
  o.w = w0 * (a0.w + a1.w) + w1 * (b0.w + b1.w);
  *(float4*)&out[(size_t)t * H_DIM + c] = o;
}

// ---------------------------------------------------------------- launch
extern "C" void kernel_launch(void* const* d_in, const int* in_sizes, int n_in,
                              void* d_out, int out_size, void* d_ws,
                              size_t ws_size, hipStream_t stream) {
  const float* x      = (const float*)d_in[0];
  const float* gate_w = (const float*)d_in[1];
  const float* w_gate = (const float*)d_in[2];
  const float* w_up   = (const float*)d_in[3];
  const float* w_down = (const float*)d_in[4];
  float* out = (float*)d_out;
  float* logits_out = out + (size_t)T_TOK * H_DIM;

  char* ws = (char*)d_ws;
  int*      counts = (int*)(ws + 0);        // 32 B
  int*      base   = (int*)(ws + 256);      // 32 B
  int*      sched  = (int*)(ws + 512);      // 256 B
  int*      meta_e = (int*)(ws + 1024);     // 16 KB
  float*    meta_w = (float*)(ws + 17408);  // 16 KB
  // 64-KB aligned big buffers
  uint16_t* xg   = (uint16_t*)(ws + 65536);               // 4096*1088*2   =  8.9 MB
  uint16_t* wgT  = (uint16_t*)(ws + 65536 + 8912896);     // 8*2816*1088*2 = 49.0 MB
  uint16_t* wuT  = (uint16_t*)(ws + 65536 + 57933824);    // 49.0 MB
  uint16_t* wdT  = (uint16_t*)(ws + 65536 + 106954752);   // 8*1024*2880*2 = 47.2 MB
  uint16_t* hbuf = (uint16_t*)(ws + 65536 + 154140672);   // 4096*2880*2   = 23.6 MB
  // ybuf0/1 reuse wuT/wgT regions (dead after gemm_gu; stream-ordered)
  float*    ybuf0 = (float*)(ws + 65536 + 8912896);       // 4096*1040*4 = 17.0 MB
  float*    ybuf1 = (float*)(ws + 65536 + 57933824);
  // total ws use: ~177.8 MB (< the 182.5 MB used successfully in R2/R3)

  hipMemsetAsync(counts, 0, E_NUM * sizeof(int), stream);
  router_kernel<<<512, 256, 0, stream>>>(x, gate_w, logits_out, counts,
                                         meta_e, meta_w);
  sched_kernel<<<1, 64, 0, stream>>>(counts, base, sched);
  gather_conv_kernel<<<T_TOK, 256, 0, stream>>>(x, base, meta_e, xg);
  transpose_conv_kernel<<<dim3(H_DIM / 64, I_DIM / 64, E_NUM), 256, 0, stream>>>(
      w_gate, wgT, H_DIM, I_DIM, KP_H);
  transpose_conv_kernel<<<dim3(H_DIM / 64, I_DIM / 64, E_NUM), 256, 0, stream>>>(
      w_up, wuT, H_DIM, I_DIM, KP_H);
  transpose_conv_kernel<<<dim3(I_DIM / 64, H_DIM / 64, E_NUM), 256, 0, stream>>>(
      w_down, wdT, I_DIM, H_DIM, KP_I);
  gemm_gu_kernel<<<512, 256, 0, stream>>>(xg, wgT, wuT, hbuf, counts, base,
                                          sched);
  // NOTE: ybuf0 overlaps wuT, ybuf1 overlaps wgT — both dead after gemm_gu
  gemm_down_kernel<<<512, 256, 0, stream>>>(hbuf, wdT, ybuf0, ybuf1, counts,
                                            base, sched);
  combine_kernel<<<T_TOK, 256, 0, stream>>>(ybuf0, ybuf1, base, meta_e, meta_w,
                                            out);
}